// Round 1
// baseline (725.754 us; speedup 1.0000x reference)
//
#include <hip/hip_runtime.h>
#include <math.h>
#include <stdint.h>

#define B 2
#define H 16
#define L 2048
#define D 64
#define NB 32     // L / 64 key/query blocks
#define TS 68     // padded LDS row stride in floats (16B-aligned rows)

// ---------------------------------------------------------------------------
// Kernel 1: per-(b,h) key mean (smooth_k), block means qm / km (km smoothed)
// ---------------------------------------------------------------------------
__global__ __launch_bounds__(256) void k_stats(const float* __restrict__ q,
                                               const float* __restrict__ k,
                                               float* __restrict__ qm,
                                               float* __restrict__ km,
                                               float* __restrict__ kmean) {
  int bh = blockIdx.x;            // 0..B*H-1
  int t = threadIdx.x;
  int d = t & 63, g = t >> 6;     // g = 0..3, each handles 8 blocks
  __shared__ float ksum[NB][D];
  __shared__ float part[4][D];
  __shared__ float kmv[D];
  const float* qb = q + (size_t)bh * L * D;
  const float* kb = k + (size_t)bh * L * D;
  float tot = 0.f;
  for (int jj = 0; jj < 8; ++jj) {
    int j = g * 8 + jj;
    const float* qp = qb + j * 64 * D + d;
    const float* kp = kb + j * 64 * D + d;
    float qs = 0.f, ks_ = 0.f;
    for (int r = 0; r < 64; ++r) { qs += qp[r * D]; ks_ += kp[r * D]; }
    qm[((size_t)bh * NB + j) * D + d] = qs * (1.f / 64.f);
    ksum[j][d] = ks_;
    tot += ks_;
  }
  part[g][d] = tot;
  __syncthreads();
  if (g == 0) {
    float m = (part[0][d] + part[1][d] + part[2][d] + part[3][d]) * (1.f / (float)L);
    kmean[bh * D + d] = m;
    kmv[d] = m;
  }
  __syncthreads();
  for (int jj = 0; jj < 8; ++jj) {
    int j = g * 8 + jj;
    km[((size_t)bh * NB + j) * D + d] = ksum[j][d] * (1.f / 64.f) - kmv[d];
  }
}

// ---------------------------------------------------------------------------
// Kernel 2: pooled flag + CDF block keep -> 32-bit mask word per (b,h,i)
// ---------------------------------------------------------------------------
__global__ __launch_bounds__(64) void k_mask(const float* __restrict__ q,
                                             const float* __restrict__ qm,
                                             const float* __restrict__ km,
                                             const float* __restrict__ cdfthreshd,
                                             const float* __restrict__ simthreshd1,
                                             uint32_t* __restrict__ maskw) {
  int blk = blockIdx.x;           // bh*32 + i
  int bh = blk >> 5, i = blk & 31;
  int h = bh & (H - 1);
  int t = threadIdx.x;            // 0..63
  __shared__ float qs[64][65];
  __shared__ float qmv[D];
  __shared__ float kms[NB][65];
  qmv[t] = qm[((size_t)bh * NB + i) * D + t];
  const float* qp = q + ((size_t)bh * L + (size_t)i * 64) * D;
  for (int r = 0; r < 64; ++r) qs[r][t] = qp[r * D + t];
  for (int e = t; e < NB * D; e += 64)
    kms[e >> 6][e & 63] = km[(size_t)bh * NB * D + e];
  __syncthreads();

  // mean cosine of this block's queries vs their mean (raw q)
  float dot = 0.f, qn2 = 0.f, qmn2 = 0.f;
  for (int dd = 0; dd < D; ++dd) {
    float a = qs[t][dd], b = qmv[dd];
    dot += a * b; qn2 += a * a; qmn2 += b * b;
  }
  float cs = dot / (sqrtf(qn2) * sqrtf(qmn2) + 1e-6f);
  for (int off = 32; off > 0; off >>= 1) cs += __shfl_xor(cs, off);
  bool pooled = (cs * (1.f / 64.f)) > simthreshd1[h];

  // block-score row i: s = qm_i . km_j * scale, softmax over 32 (lanes 0..31)
  int j = t & 31;
  float sv = 0.f;
  for (int dd = 0; dd < D; ++dd) sv += qmv[dd] * kms[j][dd];
  sv *= 0.125f;
  float mx = sv;
  for (int off = 16; off > 0; off >>= 1) mx = fmaxf(mx, __shfl_xor(mx, off, 32));
  float p = expf(sv - mx);
  float sum = p;
  for (int off = 16; off > 0; off >>= 1) sum += __shfl_xor(sum, off, 32);
  p /= sum;

  // exclusive CDF in stable-descending order, no explicit sort needed
  float excl = 0.f;
  for (int u = 0; u < 32; ++u) {
    float pu = __shfl(p, u, 32);
    if ((pu > p) || (pu == p && u < j)) excl += pu;
  }
  bool keep = excl < cdfthreshd[h];
  bool bit = (t < 32) && (keep || !pooled || j == 0);
  unsigned long long bal = __ballot(bit);
  if (t == 0) maskw[blk] = (uint32_t)(bal & 0xffffffffULL);
}

// ---------------------------------------------------------------------------
// Kernel 3: two-pass masked attention with PV pruning, per 64x64 q-block
// ---------------------------------------------------------------------------
__global__ __launch_bounds__(256) void k_attn(const float* __restrict__ q,
                                              const float* __restrict__ k,
                                              const float* __restrict__ v,
                                              const float* __restrict__ pvthreshd,
                                              const float* __restrict__ kmean,
                                              const uint32_t* __restrict__ maskw,
                                              float* __restrict__ out) {
  int blk = blockIdx.x;
  int bh = blk >> 5, i = blk & 31;
  int h = bh & (H - 1);
  int t = threadIdx.x;
  int tc = t & 15, tr = t >> 4;   // 16x16 thread grid, 4x4 elems each

  __shared__ float qs[64 * TS];
  __shared__ float kps[64 * TS];  // K tile; reused as P tile in pass B
  __shared__ float vs[64 * TS];
  __shared__ float rbm[64 * 33];  // per-(row, j) S row-max
  __shared__ float mrow[64], lrow[64], kmv[64];

  const float* qp = q + ((size_t)bh * L + (size_t)i * 64) * D;
  for (int it = 0; it < 4; ++it) {
    int idx = t + 256 * it;       // float4 index 0..1023
    int row = idx >> 4; int d4 = (idx & 15) << 2;
    float4 f = ((const float4*)qp)[idx];
    *(float4*)&qs[row * TS + d4] = f;
  }
  if (t < 64) {
    kmv[t] = kmean[bh * D + t];
    mrow[t] = -INFINITY;
    lrow[t] = 0.f;
  }
  for (int e = t; e < 64 * 33; e += 256) rbm[e] = -INFINITY;
  uint32_t mw = maskw[blk];
  __syncthreads();

  const float* kb = k + (size_t)bh * L * D;
  const float* vb = v + (size_t)bh * L * D;

  // ---- Pass A: online (m, l) + row-block maxima over mask-kept blocks ----
  for (int j = 0; j < NB; ++j) {
    if (!((mw >> j) & 1u)) continue;
    __syncthreads();
    for (int it = 0; it < 4; ++it) {
      int idx = t + 256 * it;
      int row = idx >> 4; int d4 = (idx & 15) << 2;
      float4 f = ((const float4*)(kb + (size_t)j * 64 * D))[idx];
      f.x -= kmv[d4]; f.y -= kmv[d4 + 1]; f.z -= kmv[d4 + 2]; f.w -= kmv[d4 + 3];
      *(float4*)&kps[row * TS + d4] = f;
    }
    __syncthreads();

    float acc[4][4];
#pragma unroll
    for (int rr = 0; rr < 4; ++rr)
#pragma unroll
      for (int cc = 0; cc < 4; ++cc) acc[rr][cc] = 0.f;
    for (int d4 = 0; d4 < 16; ++d4) {
      float4 qa[4], ka[4];
#pragma unroll
      for (int rr = 0; rr < 4; ++rr) qa[rr] = *(const float4*)&qs[(4 * tr + rr) * TS + 4 * d4];
#pragma unroll
      for (int cc = 0; cc < 4; ++cc) ka[cc] = *(const float4*)&kps[(4 * tc + cc) * TS + 4 * d4];
#pragma unroll
      for (int rr = 0; rr < 4; ++rr)
#pragma unroll
        for (int cc = 0; cc < 4; ++cc)
          acc[rr][cc] += qa[rr].x * ka[cc].x + qa[rr].y * ka[cc].y +
                         qa[rr].z * ka[cc].z + qa[rr].w * ka[cc].w;
    }
#pragma unroll
    for (int rr = 0; rr < 4; ++rr) {
      int r = 4 * tr + rr;
      float s0 = acc[rr][0] * 0.125f, s1 = acc[rr][1] * 0.125f;
      float s2 = acc[rr][2] * 0.125f, s3 = acc[rr][3] * 0.125f;
      float rm = fmaxf(fmaxf(s0, s1), fmaxf(s2, s3));
      for (int off = 8; off > 0; off >>= 1) rm = fmaxf(rm, __shfl_xor(rm, off, 16));
      float mold = mrow[r];
      float mnew = fmaxf(mold, rm);
      float es = __expf(s0 - mnew) + __expf(s1 - mnew) +
                 __expf(s2 - mnew) + __expf(s3 - mnew);
      for (int off = 8; off > 0; off >>= 1) es += __shfl_xor(es, off, 16);
      if (tc == 0) {
        mrow[r] = mnew;
        lrow[r] = lrow[r] * __expf(mold - mnew) + es;
        rbm[r * 33 + j] = rm;
      }
    }
  }
  __syncthreads();

  // ---- Pass B: pv gate, recompute S, P = exp(S-m)/l, O += P.V ----
  float thr = pvthreshd[h] * 1e-3f;
  float4 o4[4];
#pragma unroll
  for (int rr = 0; rr < 4; ++rr) { o4[rr].x = 0.f; o4[rr].y = 0.f; o4[rr].z = 0.f; o4[rr].w = 0.f; }

  for (int j = 0; j < NB; ++j) {
    if (!((mw >> j) & 1u)) continue;
    int lane = t & 63;
    float pb = __expf(rbm[lane * 33 + j] - mrow[lane]) / lrow[lane];
    for (int off = 32; off > 0; off >>= 1) pb = fmaxf(pb, __shfl_xor(pb, off));
    if (!(j == 0 || pb >= thr)) continue;   // uniform across block

    __syncthreads();
    for (int it = 0; it < 4; ++it) {
      int idx = t + 256 * it;
      int row = idx >> 4; int d4 = (idx & 15) << 2;
      float4 f = ((const float4*)(kb + (size_t)j * 64 * D))[idx];
      f.x -= kmv[d4]; f.y -= kmv[d4 + 1]; f.z -= kmv[d4 + 2]; f.w -= kmv[d4 + 3];
      *(float4*)&kps[row * TS + d4] = f;
      float4 g = ((const float4*)(vb + (size_t)j * 64 * D))[idx];
      *(float4*)&vs[row * TS + d4] = g;
    }
    __syncthreads();

    float acc[4][4];
#pragma unroll
    for (int rr = 0; rr < 4; ++rr)
#pragma unroll
      for (int cc = 0; cc < 4; ++cc) acc[rr][cc] = 0.f;
    for (int d4 = 0; d4 < 16; ++d4) {
      float4 qa[4], ka[4];
#pragma unroll
      for (int rr = 0; rr < 4; ++rr) qa[rr] = *(const float4*)&qs[(4 * tr + rr) * TS + 4 * d4];
#pragma unroll
      for (int cc = 0; cc < 4; ++cc) ka[cc] = *(const float4*)&kps[(4 * tc + cc) * TS + 4 * d4];
#pragma unroll
      for (int rr = 0; rr < 4; ++rr)
#pragma unroll
        for (int cc = 0; cc < 4; ++cc)
          acc[rr][cc] += qa[rr].x * ka[cc].x + qa[rr].y * ka[cc].y +
                         qa[rr].z * ka[cc].z + qa[rr].w * ka[cc].w;
    }
    __syncthreads();   // all S reads of kps done before overwriting with P
#pragma unroll
    for (int rr = 0; rr < 4; ++rr) {
      int r = 4 * tr + rr;
      float mr = mrow[r];
      float li = 1.f / lrow[r];
      float4 pv4;
      pv4.x = __expf(acc[rr][0] * 0.125f - mr) * li;
      pv4.y = __expf(acc[rr][1] * 0.125f - mr) * li;
      pv4.z = __expf(acc[rr][2] * 0.125f - mr) * li;
      pv4.w = __expf(acc[rr][3] * 0.125f - mr) * li;
      *(float4*)&kps[r * TS + 4 * tc] = pv4;
    }
    __syncthreads();

    for (int c4 = 0; c4 < 16; ++c4) {
      float4 pa[4], va[4];
#pragma unroll
      for (int rr = 0; rr < 4; ++rr) pa[rr] = *(const float4*)&kps[(4 * tr + rr) * TS + 4 * c4];
#pragma unroll
      for (int cc = 0; cc < 4; ++cc) va[cc] = *(const float4*)&vs[(4 * c4 + cc) * TS + 4 * tc];
#pragma unroll
      for (int rr = 0; rr < 4; ++rr)
#pragma unroll
        for (int cc = 0; cc < 4; ++cc) {
          float pv = ((const float*)&pa[rr])[cc];
          o4[rr].x += pv * va[cc].x;
          o4[rr].y += pv * va[cc].y;
          o4[rr].z += pv * va[cc].z;
          o4[rr].w += pv * va[cc].w;
        }
    }
  }

  float* op = out + ((size_t)bh * L + (size_t)i * 64) * D;
#pragma unroll
  for (int rr = 0; rr < 4; ++rr)
    *(float4*)&op[(4 * tr + rr) * D + 4 * tc] = o4[rr];
}

// ---------------------------------------------------------------------------
extern "C" void kernel_launch(void* const* d_in, const int* in_sizes, int n_in,
                              void* d_out, int out_size, void* d_ws, size_t ws_size,
                              hipStream_t stream) {
  (void)in_sizes; (void)n_in; (void)out_size; (void)ws_size;
  const float* q   = (const float*)d_in[0];
  const float* k   = (const float*)d_in[1];
  const float* v   = (const float*)d_in[2];
  const float* cdf = (const float*)d_in[3];
  const float* sim = (const float*)d_in[4];
  const float* pvt = (const float*)d_in[5];
  float* out = (float*)d_out;

  float* kmean = (float*)d_ws;                     // B*H*D
  float* qm    = kmean + B * H * D;                // B*H*NB*D
  float* km    = qm + (size_t)B * H * NB * D;      // B*H*NB*D
  uint32_t* maskw = (uint32_t*)(km + (size_t)B * H * NB * D);  // B*H*NB words

  k_stats<<<B * H, 256, 0, stream>>>(q, k, qm, km, kmean);
  k_mask<<<B * H * NB, 64, 0, stream>>>(q, qm, km, cdf, sim, maskw);
  k_attn<<<B * H * NB, 256, 0, stream>>>(q, k, v, pvt, kmean, maskw, out);
}

// Round 2
// 382.669 us; speedup vs baseline: 1.8966x; 1.8966x over previous
//
#include <hip/hip_runtime.h>
#include <math.h>
#include <stdint.h>

#define B 2
#define H 16
#define L 2048
#define D 64
#define NB 32      // L/64 blocks
#define KTS 72     // bf16 LDS row stride (144 B = 36 banks -> conflict-free frags)

typedef unsigned short u16;
typedef __attribute__((ext_vector_type(4))) unsigned short u16x4;
typedef __attribute__((ext_vector_type(8))) unsigned short u16x8;
typedef __attribute__((ext_vector_type(8))) short s16x8;
typedef __attribute__((ext_vector_type(4))) float f32x4;

__device__ __forceinline__ void bf16split(float f, u16& hi, u16& lo) {
  union { float f; uint32_t u; } a; a.f = f;
  uint32_t r = (a.u + 0x7fffu + ((a.u >> 16) & 1u)) >> 16;   // RNE to bf16
  hi = (u16)r;
  union { uint32_t u; float f; } b; b.u = r << 16;
  float res = f - b.f;
  union { float f; uint32_t u; } c; c.f = res;
  uint32_t r2 = (c.u + 0x7fffu + ((c.u >> 16) & 1u)) >> 16;
  lo = (u16)r2;
}

// ---------------------------------------------------------------------------
// Kernel 1: per-(b,h) key mean (smooth_k), block means qm / km (km smoothed)
// ---------------------------------------------------------------------------
__global__ __launch_bounds__(256) void k_stats(const float* __restrict__ q,
                                               const float* __restrict__ k,
                                               float* __restrict__ qm,
                                               float* __restrict__ km,
                                               float* __restrict__ kmean) {
  int bh = blockIdx.x;
  int t = threadIdx.x;
  int d = t & 63, g = t >> 6;
  __shared__ float ksum[NB][D];
  __shared__ float part[4][D];
  __shared__ float kmv[D];
  const float* qb = q + (size_t)bh * L * D;
  const float* kb = k + (size_t)bh * L * D;
  float tot = 0.f;
  for (int jj = 0; jj < 8; ++jj) {
    int j = g * 8 + jj;
    const float* qp = qb + j * 64 * D + d;
    const float* kp = kb + j * 64 * D + d;
    float qs = 0.f, ks_ = 0.f;
    for (int r = 0; r < 64; ++r) { qs += qp[r * D]; ks_ += kp[r * D]; }
    qm[((size_t)bh * NB + j) * D + d] = qs * (1.f / 64.f);
    ksum[j][d] = ks_;
    tot += ks_;
  }
  part[g][d] = tot;
  __syncthreads();
  if (g == 0) {
    float m = (part[0][d] + part[1][d] + part[2][d] + part[3][d]) * (1.f / (float)L);
    kmean[bh * D + d] = m;
    kmv[d] = m;
  }
  __syncthreads();
  for (int jj = 0; jj < 8; ++jj) {
    int j = g * 8 + jj;
    km[((size_t)bh * NB + j) * D + d] = ksum[j][d] * (1.f / 64.f) - kmv[d];
  }
}

// ---------------------------------------------------------------------------
// Prepack K: smoothed k -> bf16 hi/lo planes, row-major [bh][kr][d]
// ---------------------------------------------------------------------------
__global__ __launch_bounds__(256) void pk_k(const float* __restrict__ k,
                                            const float* __restrict__ kmean,
                                            u16* __restrict__ khi_g,
                                            u16* __restrict__ klo_g) {
  size_t o = (size_t)blockIdx.x * 256 + threadIdx.x;   // < B*H*L*D
  int bh = (int)(o >> 17);
  int d = (int)(o & 63);
  float f = k[o] - kmean[bh * 64 + d];
  u16 hi, lo; bf16split(f, hi, lo);
  khi_g[o] = hi; klo_g[o] = lo;
}

// ---------------------------------------------------------------------------
// Prepack V: transpose -> bf16 hi/lo planes, [bh][d][kr]
// ---------------------------------------------------------------------------
__global__ __launch_bounds__(256) void pk_v(const float* __restrict__ v,
                                            u16* __restrict__ vthi_g,
                                            u16* __restrict__ vtlo_g) {
  size_t o = (size_t)blockIdx.x * 256 + threadIdx.x;   // output index [bh][d][kr]
  int bh = (int)(o >> 17);
  int rem = (int)(o & 131071);
  int d = rem >> 11;
  int kr = rem & 2047;
  float f = v[(size_t)bh * L * D + (size_t)kr * D + d];  // strided read, L2/L3 absorbs
  u16 hi, lo; bf16split(f, hi, lo);
  vthi_g[o] = hi; vtlo_g[o] = lo;
}

// ---------------------------------------------------------------------------
// Kernel 2: pooled flag + CDF block keep -> 32-bit mask word per (b,h,i)
// ---------------------------------------------------------------------------
__global__ __launch_bounds__(64) void k_mask(const float* __restrict__ q,
                                             const float* __restrict__ qm,
                                             const float* __restrict__ km,
                                             const float* __restrict__ cdfthreshd,
                                             const float* __restrict__ simthreshd1,
                                             uint32_t* __restrict__ maskw) {
  int blk = blockIdx.x;
  int bh = blk >> 5, i = blk & 31;
  int h = bh & (H - 1);
  int t = threadIdx.x;
  __shared__ float qs[64][65];
  __shared__ float qmv[D];
  __shared__ float kms[NB][65];
  qmv[t] = qm[((size_t)bh * NB + i) * D + t];
  const float* qp = q + ((size_t)bh * L + (size_t)i * 64) * D;
  for (int r = 0; r < 64; ++r) qs[r][t] = qp[r * D + t];
  for (int e = t; e < NB * D; e += 64)
    kms[e >> 6][e & 63] = km[(size_t)bh * NB * D + e];
  __syncthreads();

  float dot = 0.f, qn2 = 0.f, qmn2 = 0.f;
  for (int dd = 0; dd < D; ++dd) {
    float a = qs[t][dd], b = qmv[dd];
    dot += a * b; qn2 += a * a; qmn2 += b * b;
  }
  float cs = dot / (sqrtf(qn2) * sqrtf(qmn2) + 1e-6f);
  for (int off = 32; off > 0; off >>= 1) cs += __shfl_xor(cs, off);
  bool pooled = (cs * (1.f / 64.f)) > simthreshd1[h];

  int j = t & 31;
  float sv = 0.f;
  for (int dd = 0; dd < D; ++dd) sv += qmv[dd] * kms[j][dd];
  sv *= 0.125f;
  float mx = sv;
  for (int off = 16; off > 0; off >>= 1) mx = fmaxf(mx, __shfl_xor(mx, off, 32));
  float p = expf(sv - mx);
  float sum = p;
  for (int off = 16; off > 0; off >>= 1) sum += __shfl_xor(sum, off, 32);
  p /= sum;

  float excl = 0.f;
  for (int u = 0; u < 32; ++u) {
    float pu = __shfl(p, u, 32);
    if ((pu > p) || (pu == p && u < j)) excl += pu;
  }
  bool keep = excl < cdfthreshd[h];
  bool bit = (t < 32) && (keep || !pooled || j == 0);
  unsigned long long bal = __ballot(bit);
  if (t == 0) maskw[blk] = (uint32_t)(bal & 0xffffffffULL);
}

// ---------------------------------------------------------------------------
// Kernel 3: MFMA two-pass masked attention w/ PV gate, split-bf16 precision
// ---------------------------------------------------------------------------
__device__ __forceinline__ s16x8 ldfrag(const u16* base, int row, int ks, int quad) {
  return *(const s16x8*)(base + row * KTS + ks * 32 + quad * 8);
}

__global__ __launch_bounds__(256) void k_attn(const float* __restrict__ q,
                                              const u16* __restrict__ khi_g,
                                              const u16* __restrict__ klo_g,
                                              const u16* __restrict__ vthi_g,
                                              const u16* __restrict__ vtlo_g,
                                              const float* __restrict__ pvthreshd,
                                              const uint32_t* __restrict__ maskw,
                                              float* __restrict__ out) {
  int blk = blockIdx.x;
  int bh = blk >> 5, i = blk & 31;
  int h = bh & (H - 1);
  int t = threadIdx.x;
  int lane = t & 63;
  int w = t >> 6;            // wave id 0..3, owns rows [16w, 16w+16)
  int m16 = lane & 15, quad = lane >> 4;

  __shared__ __align__(16) u16 qhi[64 * KTS], qlo[64 * KTS];
  __shared__ __align__(16) u16 kphi[64 * KTS], kplo[64 * KTS];  // K tile; P tile in pass B
  __shared__ __align__(16) u16 vthi[64 * KTS], vtlo[64 * KTS];
  __shared__ float rbm[64 * 33];
  __shared__ float mrowS[64], lrowS[64];
  __shared__ uint32_t gmaskS;

  // ---- stage Q (fp32 -> bf16 hi/lo) ----
  const float* qp = q + ((size_t)bh * L + (size_t)i * 64) * D;
  for (int it = 0; it < 4; ++it) {
    int idx = t + 256 * it;
    int r = idx >> 4, c4 = (idx & 15) * 4;
    float4 f = ((const float4*)qp)[idx];
    u16 h0, l0, h1, l1, h2, l2, h3, l3;
    bf16split(f.x, h0, l0); bf16split(f.y, h1, l1);
    bf16split(f.z, h2, l2); bf16split(f.w, h3, l3);
    *(u16x4*)&qhi[r * KTS + c4] = (u16x4){h0, h1, h2, h3};
    *(u16x4*)&qlo[r * KTS + c4] = (u16x4){l0, l1, l2, l3};
  }
  uint32_t mw = maskw[blk];

  const u16* kh = khi_g + (size_t)bh * L * D;
  const u16* kl = klo_g + (size_t)bh * L * D;
  const u16* vh = vthi_g + (size_t)bh * D * L;
  const u16* vl = vtlo_g + (size_t)bh * D * L;

  float mreg[4] = {-INFINITY, -INFINITY, -INFINITY, -INFINITY};
  float lreg[4] = {0.f, 0.f, 0.f, 0.f};

  // ---- Pass A: S stats per masked block (row state in regs, per-wave rows) ----
  for (int j = 0; j < NB; ++j) {
    if (!((mw >> j) & 1u)) continue;
    __syncthreads();
    for (int it = 0; it < 2; ++it) {
      int idx = t + 256 * it;
      int r = idx >> 3, c8 = (idx & 7) * 8;
      *(u16x8*)&kphi[r * KTS + c8] = *(const u16x8*)&kh[(size_t)(j * 64 + r) * 64 + c8];
      *(u16x8*)&kplo[r * KTS + c8] = *(const u16x8*)&kl[(size_t)(j * 64 + r) * 64 + c8];
    }
    __syncthreads();

    f32x4 acc[4];
#pragma unroll
    for (int nt = 0; nt < 4; ++nt) acc[nt] = (f32x4){0.f, 0.f, 0.f, 0.f};
#pragma unroll
    for (int ks = 0; ks < 2; ++ks) {
      s16x8 ah = ldfrag(qhi, 16 * w + m16, ks, quad);
      s16x8 al = ldfrag(qlo, 16 * w + m16, ks, quad);
#pragma unroll
      for (int nt = 0; nt < 4; ++nt) {
        s16x8 bh_ = ldfrag(kphi, 16 * nt + m16, ks, quad);
        s16x8 bl_ = ldfrag(kplo, 16 * nt + m16, ks, quad);
        acc[nt] = __builtin_amdgcn_mfma_f32_16x16x32_bf16(ah, bh_, acc[nt], 0, 0, 0);
        acc[nt] = __builtin_amdgcn_mfma_f32_16x16x32_bf16(al, bh_, acc[nt], 0, 0, 0);
        acc[nt] = __builtin_amdgcn_mfma_f32_16x16x32_bf16(ah, bl_, acc[nt], 0, 0, 0);
      }
    }
#pragma unroll
    for (int reg = 0; reg < 4; ++reg) {
      float s0 = acc[0][reg] * 0.125f, s1 = acc[1][reg] * 0.125f;
      float s2 = acc[2][reg] * 0.125f, s3 = acc[3][reg] * 0.125f;
      float rm = fmaxf(fmaxf(s0, s1), fmaxf(s2, s3));
      rm = fmaxf(rm, __shfl_xor(rm, 1));
      rm = fmaxf(rm, __shfl_xor(rm, 2));
      rm = fmaxf(rm, __shfl_xor(rm, 4));
      rm = fmaxf(rm, __shfl_xor(rm, 8));
      float mold = mreg[reg];
      float mnew = fmaxf(mold, rm);
      float es = __expf(s0 - mnew) + __expf(s1 - mnew) +
                 __expf(s2 - mnew) + __expf(s3 - mnew);
      es += __shfl_xor(es, 1);
      es += __shfl_xor(es, 2);
      es += __shfl_xor(es, 4);
      es += __shfl_xor(es, 8);
      lreg[reg] = lreg[reg] * __expf(mold - mnew) + es;
      mreg[reg] = mnew;
      if (m16 == 0) rbm[(16 * w + 4 * quad + reg) * 33 + j] = rm;
    }
  }

  // ---- PV gate per block (reference: max P in 64x64 block >= thr, or sink) ----
  if (m16 == 0) {
#pragma unroll
    for (int reg = 0; reg < 4; ++reg) {
      int r = 16 * w + 4 * quad + reg;
      mrowS[r] = mreg[reg];
      lrowS[r] = lreg[reg];
    }
  }
  __syncthreads();
  if (t < 32) {
    bool keep = (mw >> t) & 1u;
    if (keep && t != 0) {
      float thr = pvthreshd[h] * 1e-3f;
      float mp = 0.f;
      for (int r = 0; r < 64; ++r)
        mp = fmaxf(mp, __expf(rbm[r * 33 + t] - mrowS[r]) / lrowS[r]);
      keep = mp >= thr;
    }
    unsigned long long bal = __ballot(keep);
    if (t == 0) gmaskS = (uint32_t)(bal & 0xffffffffULL);
  }
  __syncthreads();
  uint32_t gm = gmaskS;

  // ---- Pass B: recompute S, P = exp(S-m)/l, O += P.V (split bf16 MFMA) ----
  float linv[4];
#pragma unroll
  for (int reg = 0; reg < 4; ++reg) linv[reg] = 1.f / lreg[reg];
  f32x4 oacc[4];
#pragma unroll
  for (int nt = 0; nt < 4; ++nt) oacc[nt] = (f32x4){0.f, 0.f, 0.f, 0.f};

  for (int j = 0; j < NB; ++j) {
    if (!((gm >> j) & 1u)) continue;
    __syncthreads();   // prior PV reads of kphi/kplo (as P) done
    for (int it = 0; it < 2; ++it) {
      int idx = t + 256 * it;
      int r = idx >> 3, c8 = (idx & 7) * 8;
      *(u16x8*)&kphi[r * KTS + c8] = *(const u16x8*)&kh[(size_t)(j * 64 + r) * 64 + c8];
      *(u16x8*)&kplo[r * KTS + c8] = *(const u16x8*)&kl[(size_t)(j * 64 + r) * 64 + c8];
      *(u16x8*)&vthi[r * KTS + c8] = *(const u16x8*)&vh[(size_t)r * L + 64 * j + c8];
      *(u16x8*)&vtlo[r * KTS + c8] = *(const u16x8*)&vl[(size_t)r * L + 64 * j + c8];
    }
    __syncthreads();

    f32x4 acc[4];
#pragma unroll
    for (int nt = 0; nt < 4; ++nt) acc[nt] = (f32x4){0.f, 0.f, 0.f, 0.f};
#pragma unroll
    for (int ks = 0; ks < 2; ++ks) {
      s16x8 ah = ldfrag(qhi, 16 * w + m16, ks, quad);
      s16x8 al = ldfrag(qlo, 16 * w + m16, ks, quad);
#pragma unroll
      for (int nt = 0; nt < 4; ++nt) {
        s16x8 bh_ = ldfrag(kphi, 16 * nt + m16, ks, quad);
        s16x8 bl_ = ldfrag(kplo, 16 * nt + m16, ks, quad);
        acc[nt] = __builtin_amdgcn_mfma_f32_16x16x32_bf16(ah, bh_, acc[nt], 0, 0, 0);
        acc[nt] = __builtin_amdgcn_mfma_f32_16x16x32_bf16(al, bh_, acc[nt], 0, 0, 0);
        acc[nt] = __builtin_amdgcn_mfma_f32_16x16x32_bf16(ah, bl_, acc[nt], 0, 0, 0);
      }
    }
    __syncthreads();   // all K-frag reads done before P overwrites the buffer

#pragma unroll
    for (int nt = 0; nt < 4; ++nt) {
#pragma unroll
      for (int reg = 0; reg < 4; ++reg) {
        float s = acc[nt][reg] * 0.125f;
        float p = __expf(s - mreg[reg]) * linv[reg];
        u16 ph, pl; bf16split(p, ph, pl);
        int r = 16 * w + 4 * quad + reg;
        int c = 16 * nt + m16;
        kphi[r * KTS + c] = ph;
        kplo[r * KTS + c] = pl;
      }
    }
    __syncthreads();

#pragma unroll
    for (int ks = 0; ks < 2; ++ks) {
      s16x8 ah = ldfrag(kphi, 16 * w + m16, ks, quad);   // P hi (A-layout rows)
      s16x8 al = ldfrag(kplo, 16 * w + m16, ks, quad);
#pragma unroll
      for (int nt = 0; nt < 4; ++nt) {
        s16x8 bh_ = ldfrag(vthi, 16 * nt + m16, ks, quad);
        s16x8 bl_ = ldfrag(vtlo, 16 * nt + m16, ks, quad);
        oacc[nt] = __builtin_amdgcn_mfma_f32_16x16x32_bf16(ah, bh_, oacc[nt], 0, 0, 0);
        oacc[nt] = __builtin_amdgcn_mfma_f32_16x16x32_bf16(al, bh_, oacc[nt], 0, 0, 0);
        oacc[nt] = __builtin_amdgcn_mfma_f32_16x16x32_bf16(ah, bl_, oacc[nt], 0, 0, 0);
      }
    }
  }

  // ---- store O (C-layout: row = 16w + 4*quad + reg, col = 16nt + m16) ----
  float* op = out + ((size_t)bh * L + (size_t)i * 64) * D;
#pragma unroll
  for (int nt = 0; nt < 4; ++nt)
#pragma unroll
    for (int reg = 0; reg < 4; ++reg)
      op[(16 * w + 4 * quad + reg) * D + 16 * nt + m16] = oacc[nt][reg];
}

// ---------------------------------------------------------------------------
extern "C" void kernel_launch(void* const* d_in, const int* in_sizes, int n_in,
                              void* d_out, int out_size, void* d_ws, size_t ws_size,
                              hipStream_t stream) {
  (void)in_sizes; (void)n_in; (void)out_size; (void)ws_size;
  const float* q   = (const float*)d_in[0];
  const float* k   = (const float*)d_in[1];
  const float* v   = (const float*)d_in[2];
  const float* cdf = (const float*)d_in[3];
  const float* sim = (const float*)d_in[4];
  const float* pvt = (const float*)d_in[5];
  float* out = (float*)d_out;

  uint8_t* w8 = (uint8_t*)d_ws;
  float* kmean = (float*)w8;                               // 2048 f  (8 KB)
  float* qm    = (float*)(w8 + 8192);                      // 65536 f (256 KB)
  float* km    = (float*)(w8 + 8192 + 262144);             // 65536 f (256 KB)
  uint32_t* maskw = (uint32_t*)(w8 + 532480);              // 1024 u32 (4 KB)
  u16* khi_g  = (u16*)(w8 + 536576);                       // 4 planes x 8 MB
  u16* klo_g  = khi_g + (size_t)B * H * L * D;
  u16* vthi_g = klo_g + (size_t)B * H * L * D;
  u16* vtlo_g = vthi_g + (size_t)B * H * L * D;

  k_stats<<<B * H, 256, 0, stream>>>(q, k, qm, km, kmean);
  pk_k<<<(B * H * L * D) / 256, 256, 0, stream>>>(k, kmean, khi_g, klo_g);
  pk_v<<<(B * H * L * D) / 256, 256, 0, stream>>>(v, vthi_g, vtlo_g);
  k_mask<<<B * H * NB, 64, 0, stream>>>(q, qm, km, cdf, sim, maskw);
  k_attn<<<B * H * NB, 256, 0, stream>>>(q, khi_g, klo_g, vthi_g, vtlo_g,
                                         pvt, maskw, out);
}

// Round 3
// 269.174 us; speedup vs baseline: 2.6962x; 1.4216x over previous
//
#include <hip/hip_runtime.h>
#include <math.h>
#include <stdint.h>

#define B 2
#define H 16
#define L 2048
#define D 64
#define NB 32
#define KTS 72     // bf16 LDS row stride (144 B -> b128-aligned, conflict-free frags)

typedef unsigned short u16;
typedef __attribute__((ext_vector_type(4))) unsigned short u16x4;
typedef __attribute__((ext_vector_type(8))) unsigned short u16x8;
typedef __attribute__((ext_vector_type(8))) short s16x8;
typedef __attribute__((ext_vector_type(4))) float f32x4;

__device__ __forceinline__ void bf16split(float f, u16& hi, u16& lo) {
  union { float f; uint32_t u; } a; a.f = f;
  uint32_t r = (a.u + 0x7fffu + ((a.u >> 16) & 1u)) >> 16;   // RNE to bf16
  hi = (u16)r;
  union { uint32_t u; float f; } b; b.u = r << 16;
  float res = f - b.f;
  union { float f; uint32_t u; } c; c.f = res;
  uint32_t r2 = (c.u + 0x7fffu + ((c.u >> 16) & 1u)) >> 16;
  lo = (u16)r2;
}

// ---------------------------------------------------------------------------
// Kernel 1a: per-(bh,j) block column sums of q and k  (1024 WGs, coalesced)
// ---------------------------------------------------------------------------
__global__ __launch_bounds__(256) void k_stats_blk(const float* __restrict__ q,
                                                   const float* __restrict__ k,
                                                   float* __restrict__ qsum,
                                                   float* __restrict__ ksum) {
  int blk = blockIdx.x;              // bh*32 + j
  int t = threadIdx.x;
  int d = t & 63, g = t >> 6;
  __shared__ float pq[4][64], pk_[4][64];
  const float* qp = q + (size_t)blk * 4096 + d;
  const float* kp = k + (size_t)blk * 4096 + d;
  float sq = 0.f, sk = 0.f;
  for (int r = g * 16; r < g * 16 + 16; ++r) { sq += qp[r * 64]; sk += kp[r * 64]; }
  pq[g][d] = sq; pk_[g][d] = sk;
  __syncthreads();
  if (t < 64) {
    qsum[(size_t)blk * 64 + t] = pq[0][t] + pq[1][t] + pq[2][t] + pq[3][t];
    ksum[(size_t)blk * 64 + t] = pk_[0][t] + pk_[1][t] + pk_[2][t] + pk_[3][t];
  }
}

// ---------------------------------------------------------------------------
// Kernel 1b: kmean per (bh,d); zero-init kmax2
// ---------------------------------------------------------------------------
__global__ __launch_bounds__(64) void k_fin(const float* __restrict__ ksum,
                                            float* __restrict__ kmean,
                                            float* __restrict__ kmax2g) {
  int bh = blockIdx.x;
  int t = threadIdx.x;
  float s = 0.f;
  for (int j = 0; j < 32; ++j) s += ksum[((size_t)bh * 32 + j) * 64 + t];
  kmean[bh * 64 + t] = s * (1.f / 2048.f);
  if (t == 0) kmax2g[bh] = 0.f;
}

// ---------------------------------------------------------------------------
// Kernel 1c: prepack K (smooth+split, straight) and V (split, transposed);
//            also max ||k_row - mu||^2 per bh via atomicMax
// ---------------------------------------------------------------------------
__global__ __launch_bounds__(256) void pk_kv(const float* __restrict__ k,
                                             const float* __restrict__ v,
                                             const float* __restrict__ kmean,
                                             u16* __restrict__ khi_g,
                                             u16* __restrict__ klo_g,
                                             u16* __restrict__ vthi_g,
                                             u16* __restrict__ vtlo_g,
                                             float* __restrict__ kmax2g) {
  int blk = blockIdx.x;               // bh*32 + j
  int bh = blk >> 5, j = blk & 31;
  int t = threadIdx.x;
  __shared__ float kmv[64];
  __shared__ float vt[64 * 65];       // f32 transpose tile, stride 65
  __shared__ unsigned bmax;
  if (t < 64) kmv[t] = kmean[bh * 64 + t];
  if (t == 0) bmax = 0u;
  __syncthreads();

  size_t base = (size_t)blk * 4096;
  float rmax = 0.f;
  for (int it = 0; it < 4; ++it) {
    int idx = t + 256 * it;
    int r = idx >> 4, c4 = (idx & 15) * 4;
    // K: smooth + split, straight store
    float4 f = *(const float4*)(k + base + r * 64 + c4);
    f.x -= kmv[c4]; f.y -= kmv[c4 + 1]; f.z -= kmv[c4 + 2]; f.w -= kmv[c4 + 3];
    u16 h0,l0,h1,l1,h2,l2,h3,l3;
    bf16split(f.x,h0,l0); bf16split(f.y,h1,l1); bf16split(f.z,h2,l2); bf16split(f.w,h3,l3);
    *(u16x4*)(khi_g + base + r * 64 + c4) = (u16x4){h0,h1,h2,h3};
    *(u16x4*)(klo_g + base + r * 64 + c4) = (u16x4){l0,l1,l2,l3};
    float ssq = f.x*f.x + f.y*f.y + f.z*f.z + f.w*f.w;
    ssq += __shfl_xor(ssq, 1); ssq += __shfl_xor(ssq, 2);
    ssq += __shfl_xor(ssq, 4); ssq += __shfl_xor(ssq, 8);
    if ((t & 15) == 0) rmax = fmaxf(rmax, ssq);
    // V: store f32 into transposed LDS tile
    float4 g = *(const float4*)(v + base + r * 64 + c4);
    vt[(c4 + 0) * 65 + r] = g.x;
    vt[(c4 + 1) * 65 + r] = g.y;
    vt[(c4 + 2) * 65 + r] = g.z;
    vt[(c4 + 3) * 65 + r] = g.w;
  }
  if ((t & 15) == 0) atomicMax(&bmax, __float_as_uint(rmax));
  __syncthreads();
  if (t == 0) atomicMax((unsigned*)(kmax2g + bh), bmax);
  // V read-out: rows d, split, coalesced u16x8 stores
  for (int it = 0; it < 2; ++it) {
    int idx = t + 256 * it;
    int d = idx >> 3, s8 = (idx & 7) * 8;
    u16x8 vh8, vl8;
    for (int ii = 0; ii < 8; ++ii) {
      u16 hh, ll; bf16split(vt[d * 65 + s8 + ii], hh, ll);
      vh8[ii] = hh; vl8[ii] = ll;
    }
    size_t o = (size_t)bh * 131072 + (size_t)d * 2048 + j * 64 + s8;
    *(u16x8*)(vthi_g + o) = vh8;
    *(u16x8*)(vtlo_g + o) = vl8;
  }
}

// ---------------------------------------------------------------------------
// Kernel 2: pooled flag + CDF block keep -> 32-bit mask word per (b,h,i)
// ---------------------------------------------------------------------------
__global__ __launch_bounds__(64) void k_mask(const float* __restrict__ q,
                                             const float* __restrict__ qsum,
                                             const float* __restrict__ ksum,
                                             const float* __restrict__ kmean,
                                             const float* __restrict__ cdfthreshd,
                                             const float* __restrict__ simthreshd1,
                                             uint32_t* __restrict__ maskw) {
  int blk = blockIdx.x;
  int bh = blk >> 5, i = blk & 31;
  int h = bh & (H - 1);
  int t = threadIdx.x;
  __shared__ float qs[64][65];
  __shared__ float qmv[D];
  __shared__ float kms[NB][65];
  qmv[t] = qsum[((size_t)bh * NB + i) * 64 + t] * (1.f / 64.f);
  const float* qp = q + ((size_t)bh * L + (size_t)i * 64) * D;
  for (int r = 0; r < 64; ++r) qs[r][t] = qp[r * D + t];
  for (int e = t; e < NB * D; e += 64)
    kms[e >> 6][e & 63] = ksum[(size_t)bh * NB * 64 + e] * (1.f / 64.f)
                        - kmean[bh * 64 + (e & 63)];
  __syncthreads();

  float dot = 0.f, qn2 = 0.f, qmn2 = 0.f;
  for (int dd = 0; dd < D; ++dd) {
    float a = qs[t][dd], b = qmv[dd];
    dot += a * b; qn2 += a * a; qmn2 += b * b;
  }
  float cs = dot / (sqrtf(qn2) * sqrtf(qmn2) + 1e-6f);
  for (int off = 32; off > 0; off >>= 1) cs += __shfl_xor(cs, off);
  bool pooled = (cs * (1.f / 64.f)) > simthreshd1[h];

  int j = t & 31;
  float sv = 0.f;
  for (int dd = 0; dd < D; ++dd) sv += qmv[dd] * kms[j][dd];
  sv *= 0.125f;
  float mx = sv;
  for (int off = 16; off > 0; off >>= 1) mx = fmaxf(mx, __shfl_xor(mx, off, 32));
  float p = expf(sv - mx);
  float sum = p;
  for (int off = 16; off > 0; off >>= 1) sum += __shfl_xor(sum, off, 32);
  p /= sum;

  float excl = 0.f;
  for (int u = 0; u < 32; ++u) {
    float pu = __shfl(p, u, 32);
    if ((pu > p) || (pu == p && u < j)) excl += pu;
  }
  bool keep = excl < cdfthreshd[h];
  bool bit = (t < 32) && (keep || !pooled || j == 0);
  unsigned long long bal = __ballot(bit);
  if (t == 0) maskw[blk] = (uint32_t)(bal & 0xffffffffULL);
}

// ---------------------------------------------------------------------------
// Kernel 3: MFMA attention, fixed-M softmax, dbuf pass A, gated pass B
// ---------------------------------------------------------------------------
__device__ __forceinline__ s16x8 ldfrag(const u16* base, int row, int ks, int quad) {
  return *(const s16x8*)(base + row * KTS + ks * 32 + quad * 8);
}

__global__ __launch_bounds__(256) void k_attn(const float* __restrict__ q,
                                              const u16* __restrict__ khi_g,
                                              const u16* __restrict__ klo_g,
                                              const u16* __restrict__ vthi_g,
                                              const u16* __restrict__ vtlo_g,
                                              const float* __restrict__ pvthreshd,
                                              const float* __restrict__ kmax2g,
                                              const uint32_t* __restrict__ maskw,
                                              float* __restrict__ out) {
  int blk = blockIdx.x;
  int bh = blk >> 5, i = blk & 31;
  int h = bh & (H - 1);
  int t = threadIdx.x;
  int lane = t & 63;
  int w = t >> 6;
  int m16 = lane & 15, quad = lane >> 4;

  __shared__ __align__(16) u16 kbuf[2][2][64 * KTS];  // [dbuf][hi/lo]; pass B: [0]=K, [1]=P
  __shared__ __align__(16) u16 vbuf[2][64 * KTS];     // Q staging, then V hi/lo
  __shared__ float rbm[64 * 33];                      // (smax - M_r) per row,block
  __shared__ float MrowS[64], linvS[64];
  __shared__ uint32_t gmaskS;

  uint32_t mw = maskw[blk];
  float thr = pvthreshd[h] * 1e-3f;
  float kmax2 = kmax2g[bh];
  const u16* kh = khi_g + (size_t)bh * 131072;
  const u16* kl = klo_g + (size_t)bh * 131072;
  const u16* vh = vthi_g + (size_t)bh * 131072;
  const u16* vl = vtlo_g + (size_t)bh * 131072;

  // ---- stage Q into vbuf (split) + row norms ----
  const float* qp = q + ((size_t)bh * L + (size_t)i * 64) * D;
  for (int it = 0; it < 4; ++it) {
    int idx = t + 256 * it;
    int r = idx >> 4, c4 = (idx & 15) * 4;
    float4 f = ((const float4*)qp)[idx];
    u16 h0,l0,h1,l1,h2,l2,h3,l3;
    bf16split(f.x,h0,l0); bf16split(f.y,h1,l1); bf16split(f.z,h2,l2); bf16split(f.w,h3,l3);
    *(u16x4*)&vbuf[0][r * KTS + c4] = (u16x4){h0,h1,h2,h3};
    *(u16x4*)&vbuf[1][r * KTS + c4] = (u16x4){l0,l1,l2,l3};
    float ssq = f.x*f.x + f.y*f.y + f.z*f.z + f.w*f.w;
    ssq += __shfl_xor(ssq, 1); ssq += __shfl_xor(ssq, 2);
    ssq += __shfl_xor(ssq, 4); ssq += __shfl_xor(ssq, 8);
    if ((t & 15) == 0) MrowS[r] = ssq;
  }
  // ---- stage first kept K block into kbuf[0] ----
  int j = (int)__builtin_ctz(mw);
  uint32_t rem = mw & (mw - 1);
  for (int it = 0; it < 2; ++it) {
    int idx = t + 256 * it;
    int r = idx >> 3, c8 = (idx & 7) * 8;
    *(u16x8*)&kbuf[0][0][r * KTS + c8] = *(const u16x8*)(kh + (size_t)(j * 64 + r) * 64 + c8);
    *(u16x8*)&kbuf[0][1][r * KTS + c8] = *(const u16x8*)(kl + (size_t)(j * 64 + r) * 64 + c8);
  }
  __syncthreads();
  if (t < 64) MrowS[t] = sqrtf(MrowS[t] * kmax2) * 0.125f;  // M_r = ||q_r||*Kmax/8
  __syncthreads();

  // ---- hoist Q fragments + M to registers ----
  s16x8 qh[2], ql[2];
  qh[0] = ldfrag(vbuf[0], 16 * w + m16, 0, quad);
  qh[1] = ldfrag(vbuf[0], 16 * w + m16, 1, quad);
  ql[0] = ldfrag(vbuf[1], 16 * w + m16, 0, quad);
  ql[1] = ldfrag(vbuf[1], 16 * w + m16, 1, quad);
  float Mreg[4];
#pragma unroll
  for (int reg = 0; reg < 4; ++reg) Mreg[reg] = MrowS[16 * w + 4 * quad + reg];

  // ---- Pass A: register-prefetch double-buffered K loop ----
  float lp[4] = {0.f, 0.f, 0.f, 0.f};
  int buf = 0;
  for (;;) {
    int nj = -1;
    u16x8 pf[4];
    if (rem) {
      nj = (int)__builtin_ctz(rem); rem &= rem - 1;
      int idx0 = t, idx1 = t + 256;
      int r0 = idx0 >> 3, c80 = (idx0 & 7) * 8;
      int r1 = idx1 >> 3, c81 = (idx1 & 7) * 8;
      pf[0] = *(const u16x8*)(kh + (size_t)(nj * 64 + r0) * 64 + c80);
      pf[1] = *(const u16x8*)(kl + (size_t)(nj * 64 + r0) * 64 + c80);
      pf[2] = *(const u16x8*)(kh + (size_t)(nj * 64 + r1) * 64 + c81);
      pf[3] = *(const u16x8*)(kl + (size_t)(nj * 64 + r1) * 64 + c81);
    }
    // compute on kbuf[buf]
    f32x4 acc[4];
#pragma unroll
    for (int nt = 0; nt < 4; ++nt) acc[nt] = (f32x4){0.f, 0.f, 0.f, 0.f};
#pragma unroll
    for (int ks = 0; ks < 2; ++ks) {
#pragma unroll
      for (int nt = 0; nt < 4; ++nt) {
        s16x8 bh_ = ldfrag(kbuf[buf][0], 16 * nt + m16, ks, quad);
        s16x8 bl_ = ldfrag(kbuf[buf][1], 16 * nt + m16, ks, quad);
        acc[nt] = __builtin_amdgcn_mfma_f32_16x16x32_bf16(qh[ks], bh_, acc[nt], 0, 0, 0);
        acc[nt] = __builtin_amdgcn_mfma_f32_16x16x32_bf16(ql[ks], bh_, acc[nt], 0, 0, 0);
        acc[nt] = __builtin_amdgcn_mfma_f32_16x16x32_bf16(qh[ks], bl_, acc[nt], 0, 0, 0);
      }
    }
#pragma unroll
    for (int reg = 0; reg < 4; ++reg) {
      float s0 = acc[0][reg] * 0.125f - Mreg[reg];
      float s1 = acc[1][reg] * 0.125f - Mreg[reg];
      float s2 = acc[2][reg] * 0.125f - Mreg[reg];
      float s3 = acc[3][reg] * 0.125f - Mreg[reg];
      lp[reg] += __expf(s0) + __expf(s1) + __expf(s2) + __expf(s3);
      float rm = fmaxf(fmaxf(s0, s1), fmaxf(s2, s3));
      rm = fmaxf(rm, __shfl_xor(rm, 1));
      rm = fmaxf(rm, __shfl_xor(rm, 2));
      rm = fmaxf(rm, __shfl_xor(rm, 4));
      rm = fmaxf(rm, __shfl_xor(rm, 8));
      if (m16 == 0) rbm[(16 * w + 4 * quad + reg) * 33 + j] = rm;
    }
    if (nj < 0) break;
    // write prefetched tile to the other buffer
    {
      int idx0 = t, idx1 = t + 256;
      int r0 = idx0 >> 3, c80 = (idx0 & 7) * 8;
      int r1 = idx1 >> 3, c81 = (idx1 & 7) * 8;
      *(u16x8*)&kbuf[buf ^ 1][0][r0 * KTS + c80] = pf[0];
      *(u16x8*)&kbuf[buf ^ 1][1][r0 * KTS + c80] = pf[1];
      *(u16x8*)&kbuf[buf ^ 1][0][r1 * KTS + c81] = pf[2];
      *(u16x8*)&kbuf[buf ^ 1][1][r1 * KTS + c81] = pf[3];
    }
    __syncthreads();
    buf ^= 1; j = nj;
  }

  // ---- finalize l (one cross-lane reduce), store linv ----
  float linvr[4];
#pragma unroll
  for (int reg = 0; reg < 4; ++reg) {
    float s = lp[reg];
    s += __shfl_xor(s, 1); s += __shfl_xor(s, 2);
    s += __shfl_xor(s, 4); s += __shfl_xor(s, 8);
    linvr[reg] = 1.f / s;
    if (m16 == 0) linvS[16 * w + 4 * quad + reg] = linvr[reg];
  }
  __syncthreads();

  // ---- PV gate ----
  if (t < 32) {
    bool keep = (mw >> t) & 1u;
    if (keep && t != 0) {
      float mp = 0.f;
      for (int r = 0; r < 64; ++r)
        mp = fmaxf(mp, __expf(rbm[r * 33 + t]) * linvS[r]);
      keep = mp >= thr;
    }
    unsigned long long bal = __ballot(keep);
    if (t == 0) gmaskS = (uint32_t)(bal & 0xffffffffULL);
  }
  __syncthreads();
  uint32_t gm = gmaskS;

  // ---- Pass B: recompute S, P = exp(S-M)*linv, O += P.V ----
  f32x4 oacc[4];
#pragma unroll
  for (int nt = 0; nt < 4; ++nt) oacc[nt] = (f32x4){0.f, 0.f, 0.f, 0.f};

  for (uint32_t g2 = gm; g2; g2 &= g2 - 1) {
    int jj = (int)__builtin_ctz(g2);
    __syncthreads();   // prior PV reads of kbuf[1]/vbuf done
    for (int it = 0; it < 2; ++it) {
      int idx = t + 256 * it;
      int r = idx >> 3, c8 = (idx & 7) * 8;
      *(u16x8*)&kbuf[0][0][r * KTS + c8] = *(const u16x8*)(kh + (size_t)(jj * 64 + r) * 64 + c8);
      *(u16x8*)&kbuf[0][1][r * KTS + c8] = *(const u16x8*)(kl + (size_t)(jj * 64 + r) * 64 + c8);
      *(u16x8*)&vbuf[0][r * KTS + c8]   = *(const u16x8*)(vh + (size_t)r * 2048 + jj * 64 + c8);
      *(u16x8*)&vbuf[1][r * KTS + c8]   = *(const u16x8*)(vl + (size_t)r * 2048 + jj * 64 + c8);
    }
    __syncthreads();

    f32x4 acc[4];
#pragma unroll
    for (int nt = 0; nt < 4; ++nt) acc[nt] = (f32x4){0.f, 0.f, 0.f, 0.f};
#pragma unroll
    for (int ks = 0; ks < 2; ++ks) {
#pragma unroll
      for (int nt = 0; nt < 4; ++nt) {
        s16x8 bh_ = ldfrag(kbuf[0][0], 16 * nt + m16, ks, quad);
        s16x8 bl_ = ldfrag(kbuf[0][1], 16 * nt + m16, ks, quad);
        acc[nt] = __builtin_amdgcn_mfma_f32_16x16x32_bf16(qh[ks], bh_, acc[nt], 0, 0, 0);
        acc[nt] = __builtin_amdgcn_mfma_f32_16x16x32_bf16(ql[ks], bh_, acc[nt], 0, 0, 0);
        acc[nt] = __builtin_amdgcn_mfma_f32_16x16x32_bf16(qh[ks], bl_, acc[nt], 0, 0, 0);
      }
    }
    // P into kbuf[1] (hi/lo); no barrier needed before (kbuf[1] reads guarded by loop-top sync)
#pragma unroll
    for (int nt = 0; nt < 4; ++nt) {
#pragma unroll
      for (int reg = 0; reg < 4; ++reg) {
        float p = __expf(acc[nt][reg] * 0.125f - Mreg[reg]) * linvr[reg];
        u16 ph, pl; bf16split(p, ph, pl);
        int r = 16 * w + 4 * quad + reg;
        int c = 16 * nt + m16;
        kbuf[1][0][r * KTS + c] = ph;
        kbuf[1][1][r * KTS + c] = pl;
      }
    }
    __syncthreads();

#pragma unroll
    for (int ks = 0; ks < 2; ++ks) {
      s16x8 ah = ldfrag(kbuf[1][0], 16 * w + m16, ks, quad);
      s16x8 al = ldfrag(kbuf[1][1], 16 * w + m16, ks, quad);
#pragma unroll
      for (int nt = 0; nt < 4; ++nt) {
        s16x8 bh_ = ldfrag(vbuf[0], 16 * nt + m16, ks, quad);
        s16x8 bl_ = ldfrag(vbuf[1], 16 * nt + m16, ks, quad);
        oacc[nt] = __builtin_amdgcn_mfma_f32_16x16x32_bf16(ah, bh_, oacc[nt], 0, 0, 0);
        oacc[nt] = __builtin_amdgcn_mfma_f32_16x16x32_bf16(al, bh_, oacc[nt], 0, 0, 0);
        oacc[nt] = __builtin_amdgcn_mfma_f32_16x16x32_bf16(ah, bl_, oacc[nt], 0, 0, 0);
      }
    }
  }

  // ---- store O ----
  float* op = out + ((size_t)bh * L + (size_t)i * 64) * D;
#pragma unroll
  for (int nt = 0; nt < 4; ++nt)
#pragma unroll
    for (int reg = 0; reg < 4; ++reg)
      op[(16 * w + 4 * quad + reg) * D + 16 * nt + m16] = oacc[nt][reg];
}

// ---------------------------------------------------------------------------
extern "C" void kernel_launch(void* const* d_in, const int* in_sizes, int n_in,
                              void* d_out, int out_size, void* d_ws, size_t ws_size,
                              hipStream_t stream) {
  (void)in_sizes; (void)n_in; (void)out_size; (void)ws_size;
  const float* q   = (const float*)d_in[0];
  const float* k   = (const float*)d_in[1];
  const float* v   = (const float*)d_in[2];
  const float* cdf = (const float*)d_in[3];
  const float* sim = (const float*)d_in[4];
  const float* pvt = (const float*)d_in[5];
  float* out = (float*)d_out;

  uint8_t* w8 = (uint8_t*)d_ws;
  float* qsum  = (float*)w8;                          // 1024*64 f  (256 KB)
  float* ksum  = (float*)(w8 + 262144);               // 256 KB
  float* kmean = (float*)(w8 + 524288);               // 8 KB
  float* kmax2 = (float*)(w8 + 532480);               // 128 B
  uint32_t* maskw = (uint32_t*)(w8 + 532608);         // 4 KB
  u16* khi_g  = (u16*)(w8 + 536704);                  // 4 planes x 8 MB
  u16* klo_g  = khi_g + (size_t)B * H * L * D;
  u16* vthi_g = klo_g + (size_t)B * H * L * D;
  u16* vtlo_g = vthi_g + (size_t)B * H * L * D;

  k_stats_blk<<<B * H * NB, 256, 0, stream>>>(q, k, qsum, ksum);
  k_fin<<<B * H, 64, 0, stream>>>(ksum, kmean, kmax2);
  pk_kv<<<B * H * NB, 256, 0, stream>>>(k, v, kmean, khi_g, klo_g, vthi_g, vtlo_g, kmax2);
  k_mask<<<B * H * NB, 64, 0, stream>>>(q, qsum, ksum, kmean, cdf, sim, maskw);
  k_attn<<<B * H * NB, 256, 0, stream>>>(q, khi_g, klo_g, vthi_g, vtlo_g,
                                         pvt, kmax2, maskw, out);
}

// Round 4
// 240.417 us; speedup vs baseline: 3.0187x; 1.1196x over previous
//
#include <hip/hip_runtime.h>
#include <math.h>
#include <stdint.h>

#define B 2
#define H 16
#define L 2048
#define D 64
#define NB 32
#define PTS 72            // P tile row stride in u16 (144 B)

typedef unsigned short u16;
typedef unsigned int u32;
typedef __attribute__((ext_vector_type(4))) unsigned short u16x4;
typedef __attribute__((ext_vector_type(8))) unsigned short u16x8;
typedef __attribute__((ext_vector_type(8))) short s16x8;
typedef __attribute__((ext_vector_type(4))) float f32x4;

__device__ __forceinline__ void bf16split(float f, u16& hi, u16& lo) {
  union { float f; uint32_t u; } a; a.f = f;
  uint32_t r = (a.u + 0x7fffu + ((a.u >> 16) & 1u)) >> 16;   // RNE to bf16
  hi = (u16)r;
  union { uint32_t u; float f; } b; b.u = r << 16;
  float res = f - b.f;
  union { float f; uint32_t u; } c; c.f = res;
  uint32_t r2 = (c.u + 0x7fffu + ((c.u >> 16) & 1u)) >> 16;
  lo = (u16)r2;
}

// ---------------------------------------------------------------------------
// k_prep: per (bh,j): K column-sums (ksum), K split hi/lo (raw, no smoothing),
//         V^T split hi/lo, per-bh max ||k_row||^2 (atomicMax)
// ---------------------------------------------------------------------------
__global__ __launch_bounds__(256) void k_prep(const float* __restrict__ k,
                                              const float* __restrict__ v,
                                              float* __restrict__ ksum,
                                              u16* __restrict__ khi_g,
                                              u16* __restrict__ klo_g,
                                              u16* __restrict__ vthi_g,
                                              u16* __restrict__ vtlo_g,
                                              float* __restrict__ kmax2g) {
  int blk = blockIdx.x, bh = blk >> 5, j = blk & 31, t = threadIdx.x;
  __shared__ float vt[64 * 65];
  __shared__ float pk_[4][64];
  __shared__ unsigned bmaxS;
  if (t == 0) bmaxS = 0u;
  size_t base = (size_t)blk * 4096;
  {
    int d = t & 63, g = t >> 6;
    float sk = 0.f;
    for (int r = g * 16; r < g * 16 + 16; ++r) sk += k[base + r * 64 + d];
    pk_[g][d] = sk;
  }
  __syncthreads();
  if (t < 64) ksum[(size_t)blk * 64 + t] = pk_[0][t] + pk_[1][t] + pk_[2][t] + pk_[3][t];

  float rmax = 0.f;
  for (int it = 0; it < 4; ++it) {
    int idx = t + 256 * it, r = idx >> 4, c4 = (idx & 15) * 4;
    float4 f = *(const float4*)(k + base + r * 64 + c4);
    u16 h0,l0,h1,l1,h2,l2,h3,l3;
    bf16split(f.x,h0,l0); bf16split(f.y,h1,l1); bf16split(f.z,h2,l2); bf16split(f.w,h3,l3);
    *(u16x4*)(khi_g + base + r * 64 + c4) = (u16x4){h0,h1,h2,h3};
    *(u16x4*)(klo_g + base + r * 64 + c4) = (u16x4){l0,l1,l2,l3};
    float ssq = f.x*f.x + f.y*f.y + f.z*f.z + f.w*f.w;
    ssq += __shfl_xor(ssq, 1); ssq += __shfl_xor(ssq, 2);
    ssq += __shfl_xor(ssq, 4); ssq += __shfl_xor(ssq, 8);
    if ((t & 15) == 0) rmax = fmaxf(rmax, ssq);
    float4 g2 = *(const float4*)(v + base + r * 64 + c4);
    vt[(c4 + 0) * 65 + r] = g2.x;
    vt[(c4 + 1) * 65 + r] = g2.y;
    vt[(c4 + 2) * 65 + r] = g2.z;
    vt[(c4 + 3) * 65 + r] = g2.w;
  }
  if ((t & 15) == 0) atomicMax(&bmaxS, __float_as_uint(rmax));
  __syncthreads();
  if (t == 0) atomicMax((unsigned*)(kmax2g + bh), bmaxS);
  for (int it = 0; it < 2; ++it) {
    int idx = t + 256 * it, d = idx >> 3, s8 = (idx & 7) * 8;
    u16x8 vh8, vl8;
    for (int ii = 0; ii < 8; ++ii) {
      u16 hh, ll; bf16split(vt[d * 65 + s8 + ii], hh, ll);
      vh8[ii] = hh; vl8[ii] = ll;
    }
    size_t o = (size_t)bh * 131072 + (size_t)d * 2048 + j * 64 + s8;
    *(u16x8*)(vthi_g + o) = vh8;
    *(u16x8*)(vtlo_g + o) = vl8;
  }
}

// ---------------------------------------------------------------------------
// k_attn: fused mask + two-pass MFMA attention (S^T = K·Q^T, O^T = V^T·P^T)
// ---------------------------------------------------------------------------
__global__ __launch_bounds__(256, 3) void k_attn(
    const float* __restrict__ q,
    const float* __restrict__ ksum,
    const u16* __restrict__ khi_g, const u16* __restrict__ klo_g,
    const u16* __restrict__ vthi_g, const u16* __restrict__ vtlo_g,
    const float* __restrict__ cdfthreshd, const float* __restrict__ simthreshd1,
    const float* __restrict__ pvthreshd, const float* __restrict__ kmax2g,
    float* __restrict__ out) {
  int blk = blockIdx.x, bh = blk >> 5, i = blk & 31, h = bh & (H - 1);
  int t = threadIdx.x, lane = t & 63, w = t >> 6;
  int m16 = lane & 15, quad = lane >> 4;

  __shared__ __align__(16) uint8_t smem[47120];
  float* qf32  = (float*)smem;                    // 64 x 68 f32 (setup only; aliases pbuf)
  u32*   rbm   = (u32*)(smem + 36864);            // 64 x 33 uint keys (-(s-M))
  float* MS    = (float*)(smem + 45312);          // 64
  float* linvS = (float*)(smem + 45568);          // 64
  float* lpart = (float*)(smem + 45824);          // [4][64]
  float* qmS   = (float*)(smem + 46848);          // 64
  int*   pooledS = (int*)(smem + 47104);
  u32*   mwS     = (u32*)(smem + 47108);
  u32*   gmS     = (u32*)(smem + 47112);
#define PBUF(b, pl) ((u16*)(smem + ((b) * 2 + (pl)) * 9216))

  const float* qg = q + ((size_t)bh * L + (size_t)i * 64) * D;
  const u16* kh = khi_g + (size_t)bh * (L * D);
  const u16* kl = klo_g + (size_t)bh * (L * D);
  const u16* vh = vthi_g + (size_t)bh * (L * D);
  const u16* vl = vtlo_g + (size_t)bh * (L * D);

  // ---- Q B-fragments straight from global (f32 -> split, registers) ----
  s16x8 qhf[4][2], qlf[4][2];
#pragma unroll
  for (int nt = 0; nt < 4; ++nt)
#pragma unroll
    for (int ks = 0; ks < 2; ++ks) {
      const float* p0 = qg + (16 * nt + m16) * 64 + ks * 32 + quad * 8;
      float4 a = *(const float4*)p0;
      float4 b2 = *(const float4*)(p0 + 4);
      u16 hh[8], ll[8];
      bf16split(a.x,  hh[0], ll[0]); bf16split(a.y,  hh[1], ll[1]);
      bf16split(a.z,  hh[2], ll[2]); bf16split(a.w,  hh[3], ll[3]);
      bf16split(b2.x, hh[4], ll[4]); bf16split(b2.y, hh[5], ll[5]);
      bf16split(b2.z, hh[6], ll[6]); bf16split(b2.w, hh[7], ll[7]);
      qhf[nt][ks] = (s16x8){(short)hh[0],(short)hh[1],(short)hh[2],(short)hh[3],
                            (short)hh[4],(short)hh[5],(short)hh[6],(short)hh[7]};
      qlf[nt][ks] = (s16x8){(short)ll[0],(short)ll[1],(short)ll[2],(short)ll[3],
                            (short)ll[4],(short)ll[5],(short)ll[6],(short)ll[7]};
    }
  // stage Q f32 for mask math
  for (int it = 0; it < 4; ++it) {
    int idx = t + 256 * it, r = idx >> 4, c4 = (idx & 15) * 4;
    *(float4*)&qf32[r * 68 + c4] = ((const float4*)qg)[idx];
  }
  for (int e = t; e < 64 * 33; e += 256) rbm[e] = 0x7F800000u;  // +inf keys
  __syncthreads();

  // ---- wave0: qm (block mean of this q-block) ----
  if (w == 0) {
    float s = 0.f;
    for (int r = 0; r < 64; ++r) s += qf32[r * 68 + lane];
    qmS[lane] = s * (1.f / 64.f);
  }
  __syncthreads();

  // ---- wave0: CDF block-keep; wave1: pooled cosine + M rows ----
  bool keepj = false;
  if (w == 0 && lane < 32) {
    int j = lane;
    const float* ksp = ksum + (size_t)bh * NB * 64 + j * 64;
    float sv = 0.f;
    for (int d = 0; d < 64; ++d) sv += qmS[d] * ksp[d];
    sv *= (1.f / 64.f) * 0.125f;     // qm . km * scale  (mean shift cancels in softmax)
    float mx = sv;
    for (int off = 16; off; off >>= 1) mx = fmaxf(mx, __shfl_xor(mx, off, 32));
    float p = expf(sv - mx);
    float sum = p;
    for (int off = 16; off; off >>= 1) sum += __shfl_xor(sum, off, 32);
    p /= sum;
    float excl = 0.f;
    for (int u = 0; u < 32; ++u) {
      float pu = __shfl(p, u, 32);
      if ((pu > p) || (pu == p && u < j)) excl += pu;
    }
    keepj = excl < cdfthreshd[h];
  }
  if (w == 1) {
    int r = lane;
    float dot = 0.f, qn2 = 0.f, qmn2 = 0.f;
    for (int d = 0; d < 64; ++d) {
      float a = qf32[r * 68 + d], b2 = qmS[d];
      dot += a * b2; qn2 += a * a; qmn2 += b2 * b2;
    }
    float cs = dot / (sqrtf(qn2) * sqrtf(qmn2) + 1e-6f);
    float su = cs;
    for (int off = 32; off; off >>= 1) su += __shfl_xor(su, off);
    if (lane == 0) *pooledS = (su * (1.f / 64.f)) > simthreshd1[h];
    MS[r] = sqrtf(qn2 * kmax2g[bh]) * 0.125f;   // M_r = ||q_r||*Kmax*scale >= |s|
  }
  __syncthreads();
  if (w == 0 && lane < 32) {
    bool bit = keepj || !(*pooledS) || (lane == 0);
    unsigned long long bal = __ballot(bit);
    if (lane == 0) *mwS = (u32)bal;
  }
  __syncthreads();
  u32 mw = *mwS;

  float Mq[4];
#pragma unroll
  for (int nt = 0; nt < 4; ++nt) Mq[nt] = MS[16 * nt + m16];

  // ---- Pass A: barrier-free; K A-frags from global; per-lane l; rbm atomics ----
  float lp[4] = {0.f, 0.f, 0.f, 0.f};
  {
    int j = (int)__builtin_ctz(mw);
    u32 rm_ = mw & (mw - 1);
    s16x8 ka[2][2], kan[2][2];
    const u16* kr0 = kh + (size_t)(j * 64 + 16 * w + m16) * 64 + quad * 8;
    const u16* kl0 = kl + (size_t)(j * 64 + 16 * w + m16) * 64 + quad * 8;
#pragma unroll
    for (int ks = 0; ks < 2; ++ks) {
      ka[ks][0] = *(const s16x8*)(kr0 + ks * 32);
      ka[ks][1] = *(const s16x8*)(kl0 + ks * 32);
    }
    for (;;) {
      int nj = -1;
      if (rm_) {
        nj = (int)__builtin_ctz(rm_); rm_ &= rm_ - 1;
        const u16* nr = kh + (size_t)(nj * 64 + 16 * w + m16) * 64 + quad * 8;
        const u16* nl = kl + (size_t)(nj * 64 + 16 * w + m16) * 64 + quad * 8;
#pragma unroll
        for (int ks = 0; ks < 2; ++ks) {
          kan[ks][0] = *(const s16x8*)(nr + ks * 32);
          kan[ks][1] = *(const s16x8*)(nl + ks * 32);
        }
      }
      f32x4 acc[4];
#pragma unroll
      for (int nt = 0; nt < 4; ++nt) acc[nt] = (f32x4){0.f, 0.f, 0.f, 0.f};
#pragma unroll
      for (int ks = 0; ks < 2; ++ks)
#pragma unroll
        for (int nt = 0; nt < 4; ++nt) {
          acc[nt] = __builtin_amdgcn_mfma_f32_16x16x32_bf16(ka[ks][0], qhf[nt][ks], acc[nt], 0, 0, 0);
          acc[nt] = __builtin_amdgcn_mfma_f32_16x16x32_bf16(ka[ks][1], qhf[nt][ks], acc[nt], 0, 0, 0);
          acc[nt] = __builtin_amdgcn_mfma_f32_16x16x32_bf16(ka[ks][0], qlf[nt][ks], acc[nt], 0, 0, 0);
        }
#pragma unroll
      for (int nt = 0; nt < 4; ++nt) {
        float vmax = -1e30f;
#pragma unroll
        for (int reg = 0; reg < 4; ++reg) {
          float s = acc[nt][reg] * 0.125f - Mq[nt];
          lp[nt] += __expf(s);
          vmax = fmaxf(vmax, s);
        }
        vmax = fmaxf(vmax, __shfl_xor(vmax, 16));
        vmax = fmaxf(vmax, __shfl_xor(vmax, 32));
        if (quad == 0)
          atomicMin(&rbm[(16 * nt + m16) * 33 + j], __float_as_uint(fmaxf(-vmax, 0.f)));
      }
      if (nj < 0) break;
#pragma unroll
      for (int ks = 0; ks < 2; ++ks) { ka[ks][0] = kan[ks][0]; ka[ks][1] = kan[ks][1]; }
      j = nj;
    }
  }
#pragma unroll
  for (int nt = 0; nt < 4; ++nt) {
    float s = lp[nt];
    s += __shfl_xor(s, 16); s += __shfl_xor(s, 32);
    if (quad == 0) lpart[w * 64 + 16 * nt + m16] = s;
  }
  __syncthreads();
  if (t < 64) linvS[t] = 1.f / (lpart[t] + lpart[64 + t] + lpart[128 + t] + lpart[192 + t]);
  __syncthreads();

  // ---- PV gate ----
  if (t < 32) {
    bool keep = (mw >> t) & 1u;
    if (keep && t != 0) {
      float thr = pvthreshd[h] * 1e-3f;
      float mp = 0.f;
      for (int r = 0; r < 64; ++r) {
        float key = __uint_as_float(rbm[r * 33 + t]);
        mp = fmaxf(mp, __expf(-key) * linvS[r]);
      }
      keep = mp >= thr;
    }
    unsigned long long bal = __ballot(keep);
    if (t == 0) *gmS = (u32)bal;
  }
  __syncthreads();
  u32 gm = *gmS;

  // ---- Pass B: S recompute -> P^T (LDS dbuf) -> O^T += V^T . P^T ----
  float linq[4];
#pragma unroll
  for (int nt = 0; nt < 4; ++nt) linq[nt] = linvS[16 * nt + m16];
  f32x4 oacc[4];
#pragma unroll
  for (int nt = 0; nt < 4; ++nt) oacc[nt] = (f32x4){0.f, 0.f, 0.f, 0.f};

  {
    int buf = 0;
    int j = -1;
    u32 g2 = gm;
    s16x8 ka[2][2];
    if (g2) {
      j = (int)__builtin_ctz(g2); g2 &= g2 - 1;
      const u16* kr0 = kh + (size_t)(j * 64 + 16 * w + m16) * 64 + quad * 8;
      const u16* kl0 = kl + (size_t)(j * 64 + 16 * w + m16) * 64 + quad * 8;
#pragma unroll
      for (int ks = 0; ks < 2; ++ks) {
        ka[ks][0] = *(const s16x8*)(kr0 + ks * 32);
        ka[ks][1] = *(const s16x8*)(kl0 + ks * 32);
      }
    }
    while (j >= 0) {
      // V^T A-frags for current j (used late -> latency hidden)
      s16x8 va[2][2];
      const u16* vr0 = vh + (size_t)(16 * w + m16) * L + j * 64 + quad * 8;
      const u16* vl0 = vl + (size_t)(16 * w + m16) * L + j * 64 + quad * 8;
#pragma unroll
      for (int ks = 0; ks < 2; ++ks) {
        va[ks][0] = *(const s16x8*)(vr0 + ks * 32);
        va[ks][1] = *(const s16x8*)(vl0 + ks * 32);
      }
      f32x4 acc[4];
#pragma unroll
      for (int nt = 0; nt < 4; ++nt) acc[nt] = (f32x4){0.f, 0.f, 0.f, 0.f};
#pragma unroll
      for (int ks = 0; ks < 2; ++ks)
#pragma unroll
        for (int nt = 0; nt < 4; ++nt) {
          acc[nt] = __builtin_amdgcn_mfma_f32_16x16x32_bf16(ka[ks][0], qhf[nt][ks], acc[nt], 0, 0, 0);
          acc[nt] = __builtin_amdgcn_mfma_f32_16x16x32_bf16(ka[ks][1], qhf[nt][ks], acc[nt], 0, 0, 0);
          acc[nt] = __builtin_amdgcn_mfma_f32_16x16x32_bf16(ka[ks][0], qlf[nt][ks], acc[nt], 0, 0, 0);
        }
      // prefetch next K while P round-trips through LDS
      int nj = -1;
      if (g2) {
        nj = (int)__builtin_ctz(g2); g2 &= g2 - 1;
        const u16* nr = kh + (size_t)(nj * 64 + 16 * w + m16) * 64 + quad * 8;
        const u16* nl = kl + (size_t)(nj * 64 + 16 * w + m16) * 64 + quad * 8;
#pragma unroll
        for (int ks = 0; ks < 2; ++ks) {
          ka[ks][0] = *(const s16x8*)(nr + ks * 32);
          ka[ks][1] = *(const s16x8*)(nl + ks * 32);
        }
      }
      // P^T -> LDS [q][k], packed b64 (regs are consecutive k)
      u16* ph_ = PBUF(buf, 0);
      u16* pl_ = PBUF(buf, 1);
#pragma unroll
      for (int nt = 0; nt < 4; ++nt) {
        u16x4 ph4, pl4;
#pragma unroll
        for (int reg = 0; reg < 4; ++reg) {
          float p = __expf(acc[nt][reg] * 0.125f - Mq[nt]) * linq[nt];
          u16 hh, ll; bf16split(p, hh, ll);
          ph4[reg] = hh; pl4[reg] = ll;
        }
        int off = (16 * nt + m16) * PTS + 16 * w + 4 * quad;
        *(u16x4*)(ph_ + off) = ph4;
        *(u16x4*)(pl_ + off) = pl4;
      }
      __syncthreads();
      // O^T strip += V^T . P^T
#pragma unroll
      for (int ks = 0; ks < 2; ++ks)
#pragma unroll
        for (int nt = 0; nt < 4; ++nt) {
          s16x8 pbh = *(const s16x8*)(ph_ + (16 * nt + m16) * PTS + ks * 32 + quad * 8);
          s16x8 pbl = *(const s16x8*)(pl_ + (16 * nt + m16) * PTS + ks * 32 + quad * 8);
          oacc[nt] = __builtin_amdgcn_mfma_f32_16x16x32_bf16(va[ks][0], pbh, oacc[nt], 0, 0, 0);
          oacc[nt] = __builtin_amdgcn_mfma_f32_16x16x32_bf16(va[ks][1], pbh, oacc[nt], 0, 0, 0);
          oacc[nt] = __builtin_amdgcn_mfma_f32_16x16x32_bf16(va[ks][0], pbl, oacc[nt], 0, 0, 0);
        }
      buf ^= 1;
      j = nj;
    }
  }

  // ---- store O: lane holds q = 16nt+m16, d = 16w+4quad+reg (contiguous) ----
  float* ob = out + ((size_t)bh * L + (size_t)i * 64) * D;
#pragma unroll
  for (int nt = 0; nt < 4; ++nt)
    *(f32x4*)(ob + (16 * nt + m16) * 64 + 16 * w + 4 * quad) = oacc[nt];
}

// ---------------------------------------------------------------------------
extern "C" void kernel_launch(void* const* d_in, const int* in_sizes, int n_in,
                              void* d_out, int out_size, void* d_ws, size_t ws_size,
                              hipStream_t stream) {
  (void)in_sizes; (void)n_in; (void)out_size; (void)ws_size;
  const float* q   = (const float*)d_in[0];
  const float* k   = (const float*)d_in[1];
  const float* v   = (const float*)d_in[2];
  const float* cdf = (const float*)d_in[3];
  const float* sim = (const float*)d_in[4];
  const float* pvt = (const float*)d_in[5];
  float* out = (float*)d_out;

  uint8_t* w8 = (uint8_t*)d_ws;
  float* ksum  = (float*)w8;                          // 1024*64 f (256 KB)
  float* kmax2 = (float*)(w8 + 262144);               // 128 B
  u16* khi_g  = (u16*)(w8 + 262400);                  // 4 planes x 8 MB
  u16* klo_g  = khi_g + (size_t)B * H * L * D;
  u16* vthi_g = klo_g + (size_t)B * H * L * D;
  u16* vtlo_g = vthi_g + (size_t)B * H * L * D;

  hipMemsetAsync(kmax2, 0, B * H * sizeof(float), stream);
  k_prep<<<B * H * NB, 256, 0, stream>>>(k, v, ksum, khi_g, klo_g, vthi_g, vtlo_g, kmax2);
  k_attn<<<B * H * NB, 256, 0, stream>>>(q, ksum, khi_g, klo_g, vthi_g, vtlo_g,
                                         cdf, sim, pvt, kmax2, out);
}